// Round 3
// baseline (27139.145 us; speedup 1.0000x reference)
//
#include <hip/hip_runtime.h>
#include <stdint.h>

// 2-layer bidirectional LSTM, B=64 S=512 IN=512 H=512. Device I/O dtype: FLOAT32
// (per reference). Internal MFMA operands bf16; gate math f32. Gate order i,f,g,o.
//
//  xg[d][g][m] = x[m] @ Wih_d^T  (MFMA GEMM, f32->bf16 converted operands),
//    m = tt*64 + b, chunked over tt if ws is small. xg stored bf16.
//  recurrence: 32 WGs (16/dir, 32 h-cols each, 2 waves); Whh slice register-resident
//  (converted to bf16 frags at preload); h broadcast via bf16 ring hglob[2 slots] with
//  per-dir agent-scope counter barrier per step; c-state f32 in registers (persisted
//  to ws between chunks). Layer-0 h-seq (hs0, bf16 [b][t][1024]) feeds layer-1 GEMM;
//  layer-1 writes f32 outputs [b][t][1024] + f32 hn/cn.
//
//  ws: [arrive 4096B][hglob 2*2*64*512*2B][cstate 2*64*512*4B (nch>1)]
//      [hs0 67MB (nch>1; else aliased into d_out)][xg_fw][xg_bw]

typedef short bf16x8 __attribute__((ext_vector_type(8)));
typedef float f32x4 __attribute__((ext_vector_type(4)));
typedef unsigned short u16;

template<int N> struct IC { static constexpr int value = N; };

__device__ __forceinline__ float bf2f(u16 u) {
  union { uint32_t i; float f; } v; v.i = ((uint32_t)u) << 16; return v.f;
}
__device__ __forceinline__ u16 f2bf(float f) {
  union { float f; uint32_t i; } v; v.f = f;
  uint32_t u = v.i;
  return (u16)((u + 0x7FFFu + ((u >> 16) & 1u)) >> 16);
}
__device__ __forceinline__ float sigf(float x) { return 1.0f / (1.0f + __expf(-x)); }
__device__ __forceinline__ float tanhf_(float x) { return 2.0f / (1.0f + __expf(-2.0f * x)) - 1.0f; }
__device__ __forceinline__ u16 u4get(ushort4 v, int r) {
  return r == 0 ? v.x : r == 1 ? v.y : r == 2 ? v.z : v.w;
}
__device__ __forceinline__ bf16x8 ld8f32(const float* p) {
  float4 a = *(const float4*)p;
  float4 b = *(const float4*)(p + 4);
  bf16x8 r;
  r[0] = (short)f2bf(a.x); r[1] = (short)f2bf(a.y);
  r[2] = (short)f2bf(a.z); r[3] = (short)f2bf(a.w);
  r[4] = (short)f2bf(b.x); r[5] = (short)f2bf(b.y);
  r[6] = (short)f2bf(b.z); r[7] = (short)f2bf(b.w);
  return r;
}

// ---------------- xg GEMM: xg[n][m-m_base] = sum_k A[m][k] * W[n][k] ----------------
// A[m][k] = Abuf[((m&63)*512 + (m>>6))*KDIM + k]; AF32=1: f32 (inputs), 0: bf16 (hs0).
// W: f32, row stride KDIM. n in [0,2048). grid (16, CM/128), block 256. xg out: bf16.
template<int KDIM, int AF32>
__global__ __launch_bounds__(256) void xg_gemm(
    const void* __restrict__ Av, const float* __restrict__ W,
    u16* __restrict__ xg, int m_base, int CM)
{
  const int tid = threadIdx.x;
  const int l = tid & 63, w = tid >> 6;
  const int wm = w & 1, wn = w >> 1;
  const int m0 = m_base + blockIdx.y * 128 + wm * 64;
  const int n0 = blockIdx.x * 128 + wn * 64;

  const float* Af = (const float*)Av;
  const u16*   Au = (const u16*)Av;
  long aoff[4];
#pragma unroll
  for (int mt = 0; mt < 4; ++mt) {
    int m = m0 + mt * 16 + (l & 15);
    aoff[mt] = ((long)(m & 63) * 512 + (m >> 6)) * KDIM + ((l >> 4) * 8);
  }
  const float* brow[4];
#pragma unroll
  for (int nt = 0; nt < 4; ++nt) {
    int n = n0 + nt * 16 + (l & 15);
    brow[nt] = W + (long)n * KDIM + ((l >> 4) * 8);
  }
  f32x4 acc[4][4] = {};
  for (int kk = 0; kk < KDIM / 32; ++kk) {
    bf16x8 a[4], b[4];
#pragma unroll
    for (int mt = 0; mt < 4; ++mt) {
      if constexpr (AF32) a[mt] = ld8f32(Af + aoff[mt] + kk * 32);
      else                a[mt] = *(const bf16x8*)(Au + aoff[mt] + kk * 32);
    }
#pragma unroll
    for (int nt = 0; nt < 4; ++nt) b[nt] = ld8f32(brow[nt] + kk * 32);
#pragma unroll
    for (int mt = 0; mt < 4; ++mt)
#pragma unroll
      for (int nt = 0; nt < 4; ++nt)
        acc[mt][nt] = __builtin_amdgcn_mfma_f32_16x16x32_bf16(a[mt], b[nt], acc[mt][nt], 0, 0, 0);
  }
  // D: col(l&15)=n, row=(l>>4)*4+r=m -> 4 consecutive m per lane -> 8B stores
#pragma unroll
  for (int nt = 0; nt < 4; ++nt) {
    int n = n0 + nt * 16 + (l & 15);
    long cb = (long)n * CM;
#pragma unroll
    for (int mt = 0; mt < 4; ++mt) {
      int mr = (m0 - m_base) + mt * 16 + (l >> 4) * 4;
      ushort4 u;
      u.x = f2bf(acc[mt][nt][0]); u.y = f2bf(acc[mt][nt][1]);
      u.z = f2bf(acc[mt][nt][2]); u.w = f2bf(acc[mt][nt][3]);
      *(ushort4*)(xg + cb + mr) = u;
    }
  }
}

// ---------------- recurrence ----------------
// grid=32: d=blockIdx.x>>4, wg=blockIdx.x&15 (h-cols [wg*32,wg*32+32)). 2 waves/block.
__global__ __launch_bounds__(128, 1) void lstm_rec(
    const u16* __restrict__ xg_fw, const u16* __restrict__ xg_bw,
    int mb_fw, int mb_bw, int CM,
    const float* __restrict__ Whh_fw, const float* __restrict__ Whh_bw,
    const float* __restrict__ bih_fw, const float* __restrict__ bhh_fw,
    const float* __restrict__ bih_bw, const float* __restrict__ bhh_bw,
    const float* __restrict__ mask,
    u16* __restrict__ hs0, float* __restrict__ outF, int out_mode,
    float* __restrict__ hn, float* __restrict__ cn,
    float* __restrict__ cstate, u16* __restrict__ hglob,
    int t_begin, int t_end, int* __restrict__ arrive)
{
  const int tid = threadIdx.x;
  const int l = tid & 63;
  const int w = tid >> 6;
  const int d = blockIdx.x >> 4;
  const int wg = blockIdx.x & 15;
  const int j0 = wg * 32;

  const float* Whh = d ? Whh_bw : Whh_fw;
  const float* bih = d ? bih_bw : bih_fw;
  const float* bhh = d ? bhh_bw : bhh_fw;
  const u16* xgd = d ? xg_bw : xg_fw;
  const int m_base = d ? mb_bw : mb_fw;
  u16* hg = hglob + d * 2 * 32768;   // [2 slots][64][512]
  int* arr = arrive + d;

  __shared__ float ex[2][2][2][2][4][64];  // [srcwave][g2][ct][mtl][r][lane] = 16KB

  // Whh fragments (bf16): B-op[k][n]=Whh[n][k]; lane: col=l&15, k=(l>>4)*8+j
  bf16x8 Bf[2][2][16];
#pragma unroll
  for (int g2 = 0; g2 < 2; ++g2) {
#pragma unroll
    for (int ct = 0; ct < 2; ++ct) {
      const int grow = (w * 2 + g2) * 512 + j0 + ct * 16 + (l & 15);
      const float* p = Whh + (long)grow * 512 + ((l >> 4) * 8);
#pragma unroll
      for (int kk = 0; kk < 16; ++kk)
        Bf[g2][ct][kk] = ld8f32(p + kk * 32);
    }
  }
  float bsum[4][2];
#pragma unroll
  for (int q = 0; q < 4; ++q)
#pragma unroll
    for (int ct = 0; ct < 2; ++ct) {
      int g = q * 512 + j0 + ct * 16 + (l & 15);
      bsum[q][ct] = bih[g] + bhh[g];
    }

  float c_[2][2][4];
  float hl[2][2][4];
#pragma unroll
  for (int ct = 0; ct < 2; ++ct)
#pragma unroll
    for (int mtl = 0; mtl < 2; ++mtl)
#pragma unroll
      for (int r = 0; r < 4; ++r) { c_[ct][mtl][r] = 0.f; hl[ct][mtl][r] = 0.f; }
  if (t_begin != 0) {
#pragma unroll
    for (int ct = 0; ct < 2; ++ct)
#pragma unroll
      for (int mtl = 0; mtl < 2; ++mtl)
#pragma unroll
        for (int r = 0; r < 4; ++r) {
          int brow = (w * 2 + mtl) * 16 + ((l >> 4) * 4) + r;
          int col = j0 + ct * 16 + (l & 15);
          c_[ct][mtl][r] = cstate[d * 32768 + brow * 512 + col];
        }
  }

  for (int t = t_begin; t < t_end; ++t) {
    const int tt = d ? (511 - t) : t;

    // xg prefetch: rows (w*2+mtl)*16+(l>>4)*4+r, col g=q*512+j0+ct*16+(l&15)
    ushort4 xv[4][2][2];
#pragma unroll
    for (int q = 0; q < 4; ++q)
#pragma unroll
      for (int ct = 0; ct < 2; ++ct)
#pragma unroll
        for (int mtl = 0; mtl < 2; ++mtl) {
          int g = q * 512 + j0 + ct * 16 + (l & 15);
          int m = tt * 64 + (w * 2 + mtl) * 16 + ((l >> 4) * 4);
          xv[q][ct][mtl] = *(const ushort4*)(xgd + (long)g * CM + (m - m_base));
        }

    f32x4 acc[2][2][4] = {};
    if (t > 0) {
      // A[m][k] = h_prev[m][k] from hglob slot t&1; lane: row=l&15, k=(l>>4)*8+j
      const u16* hp = hg + (t & 1) * 32768 + ((l & 15) * 512) + ((l >> 4) * 8);
#pragma unroll
      for (int kk = 0; kk < 16; ++kk) {
        bf16x8 a[4];
#pragma unroll
        for (int mt = 0; mt < 4; ++mt)
          a[mt] = *(const bf16x8*)(hp + mt * 16 * 512 + kk * 32);
#pragma unroll
        for (int g2 = 0; g2 < 2; ++g2)
#pragma unroll
          for (int ct = 0; ct < 2; ++ct)
#pragma unroll
            for (int mt = 0; mt < 4; ++mt)
              acc[g2][ct][mt] = __builtin_amdgcn_mfma_f32_16x16x32_bf16(
                  a[mt], Bf[g2][ct][kk], acc[g2][ct][mt], 0, 0, 0);
      }
    }

    // cross-wave exchange: wave w hands its 2 gate quadrants for the OTHER row-half
    auto do_ex = [&](auto Wc) {
      constexpr int W = decltype(Wc)::value;
#pragma unroll
      for (int g2 = 0; g2 < 2; ++g2)
#pragma unroll
        for (int ct = 0; ct < 2; ++ct)
#pragma unroll
          for (int mtl = 0; mtl < 2; ++mtl)
#pragma unroll
            for (int r = 0; r < 4; ++r)
              ex[W][g2][ct][mtl][r][l] = acc[g2][ct][(W ^ 1) * 2 + mtl][r];
    };
    if (w == 0) do_ex(IC<0>{}); else do_ex(IC<1>{});
    __syncthreads();

    auto do_pw = [&](auto Wc) {
      constexpr int W = decltype(Wc)::value;
#pragma unroll
      for (int ct = 0; ct < 2; ++ct)
#pragma unroll
        for (int mtl = 0; mtl < 2; ++mtl)
#pragma unroll
          for (int r = 0; r < 4; ++r) {
            int brow = (W * 2 + mtl) * 16 + ((l >> 4) * 4) + r;
            float gv[4];
#pragma unroll
            for (int q = 0; q < 4; ++q) {
              float raw = ((q >> 1) == W)
                            ? acc[q & 1][ct][W * 2 + mtl][r]
                            : ex[W ^ 1][q & 1][ct][mtl][r][l];
              gv[q] = raw + bf2f(u4get(xv[q][ct][mtl], r)) + bsum[q][ct];
            }
            float iv = sigf(gv[0]);
            float fv = sigf(gv[1]);
            float gg = tanhf_(gv[2]);
            float ov = sigf(gv[3]);
            float cnew = fv * c_[ct][mtl][r] + iv * gg;
            float hnew = ov * tanhf_(cnew);
            float mv = mask[brow * 512 + tt];
            float h2 = hnew * mv;
            c_[ct][mtl][r] = cnew * mv;
            hl[ct][mtl][r] = h2;
            int col = j0 + ct * 16 + (l & 15);
            u16 hb = f2bf(h2);
            hg[(((t + 1) & 1) * 64 + brow) * 512 + col] = hb;
            if (out_mode == 0)
              hs0[((long)brow * 512 + tt) * 1024 + d * 512 + col] = hb;
            else
              outF[((long)brow * 512 + tt) * 1024 + d * 512 + col] = h2;
          }
    };
    if (w == 0) do_pw(IC<0>{}); else do_pw(IC<1>{});

    if (t < t_end - 1) {
      __threadfence();            // release: h stores visible device-wide
      __syncthreads();
      if (tid == 0) {
        __hip_atomic_fetch_add(arr, 1, __ATOMIC_RELEASE, __HIP_MEMORY_SCOPE_AGENT);
        const int target = 16 * (t - t_begin + 1);
        while (__hip_atomic_load(arr, __ATOMIC_RELAXED, __HIP_MEMORY_SCOPE_AGENT) < target)
          __builtin_amdgcn_s_sleep(2);
      }
      __syncthreads();
      __threadfence();            // acquire: no stale h reads
    }
  }

  if (t_end < 512) {
#pragma unroll
    for (int ct = 0; ct < 2; ++ct)
#pragma unroll
      for (int mtl = 0; mtl < 2; ++mtl)
#pragma unroll
        for (int r = 0; r < 4; ++r) {
          int brow = (w * 2 + mtl) * 16 + ((l >> 4) * 4) + r;
          int col = j0 + ct * 16 + (l & 15);
          cstate[d * 32768 + brow * 512 + col] = c_[ct][mtl][r];
        }
  } else {
#pragma unroll
    for (int ct = 0; ct < 2; ++ct)
#pragma unroll
      for (int mtl = 0; mtl < 2; ++mtl)
#pragma unroll
        for (int r = 0; r < 4; ++r) {
          int brow = (w * 2 + mtl) * 16 + ((l >> 4) * 4) + r;
          int col = j0 + ct * 16 + (l & 15);
          hn[brow * 1024 + d * 512 + col] = hl[ct][mtl][r];
          cn[brow * 1024 + d * 512 + col] = c_[ct][mtl][r];
        }
  }
}

extern "C" void kernel_launch(void* const* d_in, const int* in_sizes, int n_in,
                              void* d_out, int out_size, void* d_ws, size_t ws_size,
                              hipStream_t stream) {
  const float* inputs = (const float*)d_in[0];
  const float* mask   = (const float*)d_in[1];
  const float* Wih[2][2] = { { (const float*)d_in[2],  (const float*)d_in[6]  },
                             { (const float*)d_in[10], (const float*)d_in[14] } };
  const float* Whh[2][2] = { { (const float*)d_in[3],  (const float*)d_in[7]  },
                             { (const float*)d_in[11], (const float*)d_in[15] } };
  const float* bih[2][2] = { { (const float*)d_in[4],  (const float*)d_in[8]  },
                             { (const float*)d_in[12], (const float*)d_in[16] } };
  const float* bhh[2][2] = { { (const float*)d_in[5],  (const float*)d_in[9]  },
                             { (const float*)d_in[13], (const float*)d_in[17] } };

  float* outputs = (float*)d_out;            // [64][512][1024] f32
  float* hn      = outputs + 33554432;       // [2][64][1024] f32
  float* cn      = hn + 131072;              // [2][64][1024] f32

  // plan: xg chunk covers TC = 512/nch steps per dir; xg stored bf16
  int nch = 0;
  for (int c : {1, 2, 4, 8, 16, 32}) {
    size_t xg_b = 2048UL * (32768 / c) * 2;
    size_t need = 4096 + 262144 + (c > 1 ? (262144UL + 67108864UL) : 0) + 2 * xg_b;
    if (ws_size >= need) { nch = c; break; }
  }
  if (!nch) {
    hipMemsetAsync(d_out, 0x49, 1024, stream);  // absmax ~8.2e5 marker: ws too small
    return;
  }
  const int TC = 512 / nch;
  const int CM = TC * 64;

  char* ws = (char*)d_ws;
  int*   arrive = (int*)ws;                          // 16 B used
  u16*   hglob  = (u16*)(ws + 4096);                 // [2][2][64][512] bf16
  float* cstate = (float*)(ws + 4096 + 262144);      // [2][64][512] f32 (nch>1)
  u16*   hs0;
  u16*   xg_fw;
  if (nch > 1) {
    hs0   = (u16*)(ws + 4096 + 262144 + 262144);
    xg_fw = (u16*)(ws + 4096 + 262144 + 262144 + 67108864);
  } else {
    hs0   = (u16*)d_out;   // bf16 hs0 aliased into outputs region (safe: GEMM precedes rec)
    xg_fw = (u16*)(ws + 4096 + 262144);
  }
  u16* xg_bw = xg_fw + 2048L * CM;

  for (int layer = 0; layer < 2; ++layer) {
    for (int cc = 0; cc < nch; ++cc) {
      const int mb_fw = cc * CM;
      const int mb_bw = 32768 - (cc + 1) * CM;
      dim3 g(16, CM / 128);
      if (layer == 0) {
        xg_gemm<512, 1><<<g, 256, 0, stream>>>(inputs, Wih[0][0], xg_fw, mb_fw, CM);
        xg_gemm<512, 1><<<g, 256, 0, stream>>>(inputs, Wih[0][1], xg_bw, mb_bw, CM);
      } else {
        xg_gemm<1024, 0><<<g, 256, 0, stream>>>(hs0, Wih[1][0], xg_fw, mb_fw, CM);
        xg_gemm<1024, 0><<<g, 256, 0, stream>>>(hs0, Wih[1][1], xg_bw, mb_bw, CM);
      }
      hipMemsetAsync(arrive, 0, 16, stream);
      lstm_rec<<<32, 128, 0, stream>>>(
          xg_fw, xg_bw, mb_fw, mb_bw, CM,
          Whh[layer][0], Whh[layer][1],
          bih[layer][0], bhh[layer][0], bih[layer][1], bhh[layer][1],
          mask, hs0, outputs, layer,
          hn + layer * 65536, cn + layer * 65536,
          cstate, hglob, cc * TC, (cc + 1) * TC, arrive);
    }
  }
}